// Round 14
// baseline (1954.692 us; speedup 1.0000x reference)
//
#include <hip/hip_runtime.h>

#define TT 1024
#define NB 32
#define NJ 128
#define NI 512
#define KD 16
#define LVL 1048576   // shorts per level in WF (512*2048)

typedef short bf16x8 __attribute__((ext_vector_type(8)));
typedef float floatx4 __attribute__((ext_vector_type(4)));

struct S3 { short h, m, l; };

// 3-way bf16 truncation split: v = h + m + l + O(2^-24 v). Residuals exact.
__device__ __forceinline__ S3 split3(float v) {
    S3 o;
    unsigned hb = __float_as_uint(v) & 0xFFFF0000u;
    float hf = __uint_as_float(hb);
    float r1 = v - hf;
    unsigned mb = __float_as_uint(r1) & 0xFFFF0000u;
    float mf = __uint_as_float(mb);
    float r2 = r1 - mf;
    unsigned lb = __float_as_uint(r2) & 0xFFFF0000u;
    o.h = (short)(hb >> 16);
    o.m = (short)(mb >> 16);
    o.l = (short)(lb >> 16);
    return o;
}

// ---------------- DCLS: W in 3-level bf16 MFMA B-frag layout [R10-proven] ----------------
// k = d*128 + j. WF[lvl][ig=i>>4][ko=k>>3][c16=i&15][kq=k&7]: a wave's B-frag
// load (4 k-octets x 16 cols) is one contiguous 1KB block = 1 dwordx4/lane.
__global__ __launch_bounds__(256) void dcls_kern(const float* __restrict__ w,
                                                 const float* __restrict__ P,
                                                 short* __restrict__ WF) {
    int idx = blockIdx.x * 256 + threadIdx.x;   // idx = i*128 + j
    int j = idx & (NJ - 1);
    int i = idx >> 7;
    float wv = w[i * NJ + j];
    float c  = P[i * NJ + j] + (float)(KD / 2);
    float g[KD];
    float s = 0.f;
#pragma unroll
    for (int k = 0; k < KD; ++k) {
        float u = (float)k - c;
        g[k] = expf(-2.0f * u * u);
        s += g[k];
    }
    float inv = wv / (s + 1e-7f);
    size_t base = (size_t)(i >> 4) * 32768 + (size_t)(j >> 3) * 128 + (i & 15) * 8 + (j & 7);
#pragma unroll
    for (int d = 0; d < KD; ++d) {
        S3 sp = split3(g[(KD - 1) - d] * inv);   // conv flip
        size_t off = base + (size_t)d * 2048;
        WF[off]           = sp.h;
        WF[off + LVL]     = sp.m;
        WF[off + 2 * LVL] = sp.l;
    }
}

// ---------------- MFMA conv: y[t,b,i] = sum_{d,j} W[i][d*128+j] * x[t-d,b,j] ----
// 128t x 256i tile, 512 threads = 8 waves (2 wm x 4 wn, wave-tile 64x64).
// vs R10: MFMA per block 2x at SAME x-stage cost -> per-thread staging halves
// (8 split3, 3 ds_writes per K-step); grid = 512 blocks = 2/CU in ONE pass;
// 16 waves/CU = 4/SIMD (deeper MFMA queue). W direct from global frag layout.
// 6 MFMA products: AhWh + AhWm + AmWh + AmWm + AhWl + AlWh.
__global__ __launch_bounds__(512, 4) void conv_mfma(const float* __restrict__ x,
                                                    const short* __restrict__ WF,
                                                    float* __restrict__ y) {
    __shared__ __align__(16) short PA[128][64];   // [Ah | Am], 8x16B chunks/row
    __shared__ __align__(16) short PL[128][64];   // [Al | --]

    const int t0 = blockIdx.x * 128;
    const int i0 = blockIdx.y * 256;
    const int b  = blockIdx.z;
    const int tid = threadIdx.x;

    const int ch   = tid & 3;            // staging: 4 chunks x 8 floats = 32 cols
    const int rw   = tid >> 2;           // 0..127: one row per thread
    const int l    = tid & 63;
    const int wv   = tid >> 6;           // wave 0..7
    const int lr16 = l & 15;
    const int kb   = l >> 4;             // k-octet 0..3
    const int wm   = wv >> 2;            // 0..1 -> 64 t-rows
    const int wn   = wv & 3;             // 0..3 -> 64 i-cols

    const short* pnf[4];
#pragma unroll
    for (int nf = 0; nf < 4; ++nf) {
        int ig = (i0 + wn * 64 + nf * 16) >> 4;
        pnf[nf] = WF + (size_t)ig * 32768 + l * 8;
    }

    floatx4 acc[4][4];
#pragma unroll
    for (int mf = 0; mf < 4; ++mf)
#pragma unroll
        for (int nf = 0; nf < 4; ++nf)
#pragma unroll
            for (int e = 0; e < 4; ++e) acc[mf][nf][e] = 0.f;

    float4 ga[2];
    bf16x8 W0h[4], W0m[4], W0l[4], W1h[4], W1m[4], W1l[4];

#define LOADW(K, H, M, L_) {                                                    \
    int koff = ((((K) >> 2) * 16 + ((K) & 3) * 4)) * 128;                       \
    _Pragma("unroll") for (int nf = 0; nf < 4; ++nf) {                          \
        const short* p = pnf[nf] + koff;                                        \
        H[nf]  = *(const bf16x8*)(p);                                           \
        M[nf]  = *(const bf16x8*)(p + LVL);                                     \
        L_[nf] = *(const bf16x8*)(p + 2 * LVL); } }

#define LOADX(K) {                                                              \
    int dn = (K) >> 2, j0n = ((K) & 3) << 5;                                    \
    int t = t0 + rw - dn;                                                       \
    float4 z4 = make_float4(0.f, 0.f, 0.f, 0.f);                                \
    ga[0] = z4; ga[1] = z4;                                                     \
    if (t >= 0) {                                                               \
        const float* ax = x + ((size_t)t * NB + b) * NJ + j0n + ch * 8;         \
        ga[0] = *(const float4*)ax;                                             \
        ga[1] = *(const float4*)(ax + 4); } }

#define STAGEW() {                                                              \
    int key = rw & 7;                                                           \
    char* rowA = (char*)PA + rw * 128;                                          \
    char* rowL = (char*)PL + rw * 128;                                          \
    S3 a0 = split3(ga[0].x), a1 = split3(ga[0].y),                              \
       a2 = split3(ga[0].z), a3 = split3(ga[0].w),                              \
       a4 = split3(ga[1].x), a5 = split3(ga[1].y),                              \
       a6 = split3(ga[1].z), a7 = split3(ga[1].w);                              \
    bf16x8 h8, m8, l8;                                                          \
    h8[0]=a0.h; h8[1]=a1.h; h8[2]=a2.h; h8[3]=a3.h;                             \
    h8[4]=a4.h; h8[5]=a5.h; h8[6]=a6.h; h8[7]=a7.h;                             \
    m8[0]=a0.m; m8[1]=a1.m; m8[2]=a2.m; m8[3]=a3.m;                             \
    m8[4]=a4.m; m8[5]=a5.m; m8[6]=a6.m; m8[7]=a7.m;                             \
    l8[0]=a0.l; l8[1]=a1.l; l8[2]=a2.l; l8[3]=a3.l;                             \
    l8[4]=a4.l; l8[5]=a5.l; l8[6]=a6.l; l8[7]=a7.l;                             \
    *(bf16x8*)(rowA + ((ch ^ key) * 16))       = h8;                            \
    *(bf16x8*)(rowA + (((ch + 4) ^ key) * 16)) = m8;                            \
    *(bf16x8*)(rowL + ((ch ^ key) * 16))       = l8; }

#define DOMFMA(CH, CM, CL) {                                                    \
    _Pragma("unroll") for (int mf = 0; mf < 4; ++mf) {                          \
        int row = wm * 64 + mf * 16 + lr16;                                     \
        int key = row & 7;                                                      \
        const char* rowA = (const char*)PA + row * 128;                         \
        const char* rowL = (const char*)PL + row * 128;                         \
        bf16x8 ah = *(const bf16x8*)(rowA + ((kb ^ key) * 16));                 \
        bf16x8 am = *(const bf16x8*)(rowA + (((kb + 4) ^ key) * 16));           \
        bf16x8 al = *(const bf16x8*)(rowL + ((kb ^ key) * 16));                 \
        _Pragma("unroll") for (int nf = 0; nf < 4; ++nf)                        \
            acc[mf][nf] = __builtin_amdgcn_mfma_f32_16x16x32_bf16(ah, CH[nf], acc[mf][nf], 0, 0, 0); \
        _Pragma("unroll") for (int nf = 0; nf < 4; ++nf)                        \
            acc[mf][nf] = __builtin_amdgcn_mfma_f32_16x16x32_bf16(ah, CM[nf], acc[mf][nf], 0, 0, 0); \
        _Pragma("unroll") for (int nf = 0; nf < 4; ++nf)                        \
            acc[mf][nf] = __builtin_amdgcn_mfma_f32_16x16x32_bf16(am, CH[nf], acc[mf][nf], 0, 0, 0); \
        _Pragma("unroll") for (int nf = 0; nf < 4; ++nf)                        \
            acc[mf][nf] = __builtin_amdgcn_mfma_f32_16x16x32_bf16(am, CM[nf], acc[mf][nf], 0, 0, 0); \
        _Pragma("unroll") for (int nf = 0; nf < 4; ++nf)                        \
            acc[mf][nf] = __builtin_amdgcn_mfma_f32_16x16x32_bf16(ah, CL[nf], acc[mf][nf], 0, 0, 0); \
        _Pragma("unroll") for (int nf = 0; nf < 4; ++nf)                        \
            acc[mf][nf] = __builtin_amdgcn_mfma_f32_16x16x32_bf16(al, CH[nf], acc[mf][nf], 0, 0, 0); \
    } }

#define STEP(K, CH, CM, CL, NH, NM, NL) {                                       \
    __syncthreads();                                                            \
    STAGEW()                                                                    \
    __syncthreads();                                                            \
    if ((K) + 1 < 64) { LOADX((K) + 1) LOADW((K) + 1, NH, NM, NL) }             \
    DOMFMA(CH, CM, CL) }

    // prologue: x + W for K-step 0
    LOADX(0)
    LOADW(0, W0h, W0m, W0l)

#pragma unroll 1
    for (int kk = 0; kk < 64; kk += 2) {
        STEP(kk,     W0h, W0m, W0l, W1h, W1m, W1l)
        STEP(kk + 1, W1h, W1m, W1l, W0h, W0m, W0l)
    }
#undef LOADW
#undef LOADX
#undef STAGEW
#undef DOMFMA
#undef STEP

    // ---- epilogue: C/D layout col=lane&15, row=(lane>>4)*4+reg [m89-verified] ----
#pragma unroll
    for (int mf = 0; mf < 4; ++mf)
#pragma unroll
        for (int nf = 0; nf < 4; ++nf) {
            int ic = i0 + wn * 64 + nf * 16 + lr16;
#pragma unroll
            for (int q = 0; q < 4; ++q) {
                int t = t0 + wm * 64 + mf * 16 + kb * 4 + q;
                y[((size_t)t * NB + b) * NI + ic] = acc[mf][nf][q];
            }
        }
}

// ---------------- BN stats pass 1: per-block partial sum/sumsq over 128 rows ----
__global__ __launch_bounds__(256) void red1(const float* __restrict__ y,
                                            float* __restrict__ part) {
    int r0 = blockIdx.x * 128;
    int c  = threadIdx.x;
    float s0 = 0.f, q0 = 0.f, s1 = 0.f, q1 = 0.f;
#pragma unroll 4
    for (int r = 0; r < 128; ++r) {
        float v0 = y[(size_t)(r0 + r) * NI + c];
        float v1 = y[(size_t)(r0 + r) * NI + c + 256];
        s0 += v0; q0 = fmaf(v0, v0, q0);
        s1 += v1; q1 = fmaf(v1, v1, q1);
    }
    part[blockIdx.x * NI + c]            = s0;
    part[blockIdx.x * NI + c + 256]      = s1;
    part[256 * NI + blockIdx.x * NI + c]       = q0;
    part[256 * NI + blockIdx.x * NI + c + 256] = q1;
}

// ---------------- BN stats pass 2: combine partials (double), emit scale/bias ----
__global__ __launch_bounds__(512) void red2(const float* __restrict__ part,
                                            const float* __restrict__ gamma,
                                            const float* __restrict__ bbeta,
                                            float* __restrict__ sb) {
    int c = threadIdx.x;
    double s = 0.0, q = 0.0;
#pragma unroll 8
    for (int p = 0; p < 256; ++p) {
        s += (double)part[p * NI + c];
        q += (double)part[256 * NI + p * NI + c];
    }
    double mean = s / 32768.0;
    double var  = q / 32768.0 - mean * mean;
    double scale = (double)gamma[c] / sqrt(var + 1e-5);
    sb[c]      = (float)scale;
    sb[NI + c] = (float)((double)bbeta[c] - mean * scale);
}

// ---------------- soft-reset LIF scan, in-place over y (=d_out) ----------------
__global__ __launch_bounds__(64) void scan_kern(float* __restrict__ y,
                                                const float* __restrict__ sb,
                                                const float* __restrict__ beta,
                                                const float* __restrict__ U0) {
    int g = blockIdx.x * 64 + threadIdx.x;   // 0..16383 = b*512 + i
    int i = g & (NI - 1);
    float scale = sb[i];
    float bias  = sb[NI + i];
    float bet = beta[i];
    float omb = 1.f - bet;
    float u = U0[g];
    float s = 0.f;
    float* yp = y + g;

    float A[32], Bv[32];
#pragma unroll
    for (int r = 0; r < 32; ++r) A[r] = yp[(size_t)r * 16384];

    for (int t0 = 0; t0 < TT; t0 += 64) {
#pragma unroll
        for (int r = 0; r < 32; ++r) Bv[r] = yp[(size_t)(t0 + 32 + r) * 16384];
#pragma unroll
        for (int r = 0; r < 32; ++r) {
            float z = fmaf(A[r], scale, bias);
            u = fmaf(bet, u - s, omb * z);
            s = (u >= 1.f) ? 1.f : 0.f;
            yp[(size_t)(t0 + r) * 16384] = s;
        }
        if (t0 + 64 < TT) {
#pragma unroll
            for (int r = 0; r < 32; ++r) A[r] = yp[(size_t)(t0 + 64 + r) * 16384];
        }
#pragma unroll
        for (int r = 0; r < 32; ++r) {
            float z = fmaf(Bv[r], scale, bias);
            u = fmaf(bet, u - s, omb * z);
            s = (u >= 1.f) ? 1.f : 0.f;
            yp[(size_t)(t0 + 32 + r) * 16384] = s;
        }
    }
}

extern "C" void kernel_launch(void* const* d_in, const int* in_sizes, int n_in,
                              void* d_out, int out_size, void* d_ws, size_t ws_size,
                              hipStream_t stream) {
    const float* x       = (const float*)d_in[0];
    const float* delay_w = (const float*)d_in[1];
    const float* delay_P = (const float*)d_in[2];
    const float* beta    = (const float*)d_in[3];
    const float* bn_g    = (const float*)d_in[4];
    const float* bn_b    = (const float*)d_in[5];
    const float* U0      = (const float*)d_in[6];
    float* y = (float*)d_out;

    // ws layout (6 MiB total, R10-proven): WF occupies [0, 6 MiB). part/sb ALIAS
    // WF's space — safe because kernels serialize on the stream: dcls writes WF,
    // conv reads WF, THEN red1 clobbers [0,1 MiB) with partials, red2 writes sb.
    // Every buffer fully rewritten before each read -> deterministic under replay.
    short* WF   = (short*)d_ws;
    float* part = (float*)d_ws;
    float* sb   = (float*)d_ws + 2 * 256 * NI;

    dcls_kern<<<dim3(NI * NJ / 256), dim3(256), 0, stream>>>(delay_w, delay_P, WF);
    conv_mfma<<<dim3(TT / 128, NI / 256, NB), dim3(512), 0, stream>>>(x, WF, y);
    red1<<<dim3(TT * NB / 128), dim3(256), 0, stream>>>(y, part);
    red2<<<dim3(1), dim3(512), 0, stream>>>(part, bn_g, bn_b, sb);
    scan_kern<<<dim3(NB * NI / 64), dim3(64), 0, stream>>>(y, sb, beta, U0);
}

// Round 15
// 357.437 us; speedup vs baseline: 5.4686x; 5.4686x over previous
//
#include <hip/hip_runtime.h>

#define TT 1024
#define NB 32
#define NJ 128
#define NI 512
#define KD 16
#define LVL 1048576   // shorts per level in WF (512*2048)

typedef short bf16x8 __attribute__((ext_vector_type(8)));
typedef float floatx4 __attribute__((ext_vector_type(4)));

struct S3 { short h, m, l; };

// 3-way bf16 truncation split: v = h + m + l + O(2^-24 v). Residuals exact.
__device__ __forceinline__ S3 split3(float v) {
    S3 o;
    unsigned hb = __float_as_uint(v) & 0xFFFF0000u;
    float hf = __uint_as_float(hb);
    float r1 = v - hf;
    unsigned mb = __float_as_uint(r1) & 0xFFFF0000u;
    float mf = __uint_as_float(mb);
    float r2 = r1 - mf;
    unsigned lb = __float_as_uint(r2) & 0xFFFF0000u;
    o.h = (short)(hb >> 16);
    o.m = (short)(mb >> 16);
    o.l = (short)(lb >> 16);
    return o;
}

// ---------------- DCLS: W in 3-level bf16 MFMA B-frag layout [R10-proven] ----------------
// k = d*128 + j. WF[lvl][ig=i>>4][ko=k>>3][c16=i&15][kq=k&7]: a wave's B-frag
// load (4 k-octets x 16 cols) is one contiguous 1KB block = 1 dwordx4/lane.
__global__ __launch_bounds__(256) void dcls_kern(const float* __restrict__ w,
                                                 const float* __restrict__ P,
                                                 short* __restrict__ WF) {
    int idx = blockIdx.x * 256 + threadIdx.x;   // idx = i*128 + j
    int j = idx & (NJ - 1);
    int i = idx >> 7;
    float wv = w[i * NJ + j];
    float c  = P[i * NJ + j] + (float)(KD / 2);
    float g[KD];
    float s = 0.f;
#pragma unroll
    for (int k = 0; k < KD; ++k) {
        float u = (float)k - c;
        g[k] = expf(-2.0f * u * u);
        s += g[k];
    }
    float inv = wv / (s + 1e-7f);
    size_t base = (size_t)(i >> 4) * 32768 + (size_t)(j >> 3) * 128 + (i & 15) * 8 + (j & 7);
#pragma unroll
    for (int d = 0; d < KD; ++d) {
        S3 sp = split3(g[(KD - 1) - d] * inv);   // conv flip
        size_t off = base + (size_t)d * 2048;
        WF[off]           = sp.h;
        WF[off + LVL]     = sp.m;
        WF[off + 2 * LVL] = sp.l;
    }
}

// ---------------- MFMA conv: y[t,b,i] = sum_{d,j} W[i][d*128+j] * x[t-d,b,j] ----
// 256t x 256i tile, 512 threads = 8 waves (2 wm x 4 wn, wave-tile 128x64).
// Grid = 4 x 2 x 32 = 256 blocks = EXACTLY 1/CU, single pass (R10 ran 2 passes).
// Per-thread staging same as R10 (16 split3) but 2x MFMA per K-step -> stage
// ratio halves. W single-buffered from global frag layout (acc=128 + W=48 +
// ga=16 + addr ~ 220 VGPR; launch_bounds(512,2) caps at 256 -> NO SPILL,
// the R14 failure). LDS 64KB static (R13-proven size). 6 MFMA products.
__global__ __launch_bounds__(512, 2) void conv_mfma(const float* __restrict__ x,
                                                    const short* __restrict__ WF,
                                                    float* __restrict__ y) {
    __shared__ __align__(16) short PA[256][64];   // [Ah | Am], 8x16B chunks/row (32 KB)
    __shared__ __align__(16) short PL[256][64];   // [Al | --]             (32 KB)

    const int t0 = blockIdx.x * 256;
    const int i0 = blockIdx.y * 256;
    const int b  = blockIdx.z;
    const int tid = threadIdx.x;

    const int ch   = tid & 3;            // staging: 4 chunks x 8 floats = 32 cols
    const int rw   = tid >> 2;           // 0..127; thread stages rows rw, rw+128
    const int l    = tid & 63;
    const int wv   = tid >> 6;           // wave 0..7
    const int lr16 = l & 15;
    const int kb   = l >> 4;             // k-octet 0..3
    const int wm   = wv >> 2;            // 0..1 -> 128 t-rows
    const int wn   = wv & 3;             // 0..3 -> 64 i-cols

    const short* pnf[4];
#pragma unroll
    for (int nf = 0; nf < 4; ++nf) {
        int ig = (i0 + wn * 64 + nf * 16) >> 4;
        pnf[nf] = WF + (size_t)ig * 32768 + l * 8;
    }

    floatx4 acc[8][4];
#pragma unroll
    for (int mf = 0; mf < 8; ++mf)
#pragma unroll
        for (int nf = 0; nf < 4; ++nf)
#pragma unroll
            for (int e = 0; e < 4; ++e) acc[mf][nf][e] = 0.f;

    float4 ga[2][2];
    bf16x8 Wh[4], Wm[4], Wl[4];

#define LOADW(K) {                                                              \
    int koff = ((((K) >> 2) * 16 + ((K) & 3) * 4)) * 128;                       \
    _Pragma("unroll") for (int nf = 0; nf < 4; ++nf) {                          \
        const short* p = pnf[nf] + koff;                                        \
        Wh[nf] = *(const bf16x8*)(p);                                           \
        Wm[nf] = *(const bf16x8*)(p + LVL);                                     \
        Wl[nf] = *(const bf16x8*)(p + 2 * LVL); } }

#define LOADX(K) {                                                              \
    int dn = (K) >> 2, j0n = ((K) & 3) << 5;                                    \
    _Pragma("unroll") for (int s = 0; s < 2; ++s) {                             \
        int t = t0 + rw + s * 128 - dn;                                         \
        float4 z4 = make_float4(0.f, 0.f, 0.f, 0.f);                            \
        ga[s][0] = z4; ga[s][1] = z4;                                           \
        if (t >= 0) {                                                           \
            const float* ax = x + ((size_t)t * NB + b) * NJ + j0n + ch * 8;     \
            ga[s][0] = *(const float4*)ax;                                      \
            ga[s][1] = *(const float4*)(ax + 4); } } }

#define STAGEW() {                                                              \
    _Pragma("unroll") for (int s = 0; s < 2; ++s) {                             \
        int r = rw + s * 128;                                                   \
        int key = r & 7;                                                        \
        char* rowA = (char*)PA + r * 128;                                       \
        char* rowL = (char*)PL + r * 128;                                       \
        S3 a0 = split3(ga[s][0].x), a1 = split3(ga[s][0].y),                    \
           a2 = split3(ga[s][0].z), a3 = split3(ga[s][0].w),                    \
           a4 = split3(ga[s][1].x), a5 = split3(ga[s][1].y),                    \
           a6 = split3(ga[s][1].z), a7 = split3(ga[s][1].w);                    \
        bf16x8 h8, m8, l8;                                                      \
        h8[0]=a0.h; h8[1]=a1.h; h8[2]=a2.h; h8[3]=a3.h;                         \
        h8[4]=a4.h; h8[5]=a5.h; h8[6]=a6.h; h8[7]=a7.h;                         \
        m8[0]=a0.m; m8[1]=a1.m; m8[2]=a2.m; m8[3]=a3.m;                         \
        m8[4]=a4.m; m8[5]=a5.m; m8[6]=a6.m; m8[7]=a7.m;                         \
        l8[0]=a0.l; l8[1]=a1.l; l8[2]=a2.l; l8[3]=a3.l;                         \
        l8[4]=a4.l; l8[5]=a5.l; l8[6]=a6.l; l8[7]=a7.l;                         \
        *(bf16x8*)(rowA + ((ch ^ key) * 16))       = h8;                        \
        *(bf16x8*)(rowA + (((ch + 4) ^ key) * 16)) = m8;                        \
        *(bf16x8*)(rowL + ((ch ^ key) * 16))       = l8; } }

#define DOMFMA() {                                                              \
    _Pragma("unroll") for (int mf = 0; mf < 8; ++mf) {                          \
        int row = wm * 128 + mf * 16 + lr16;                                    \
        int key = row & 7;                                                      \
        const char* rowA = (const char*)PA + row * 128;                         \
        const char* rowL = (const char*)PL + row * 128;                         \
        bf16x8 ah = *(const bf16x8*)(rowA + ((kb ^ key) * 16));                 \
        bf16x8 am = *(const bf16x8*)(rowA + (((kb + 4) ^ key) * 16));           \
        bf16x8 al = *(const bf16x8*)(rowL + ((kb ^ key) * 16));                 \
        _Pragma("unroll") for (int nf = 0; nf < 4; ++nf)                        \
            acc[mf][nf] = __builtin_amdgcn_mfma_f32_16x16x32_bf16(ah, Wh[nf], acc[mf][nf], 0, 0, 0); \
        _Pragma("unroll") for (int nf = 0; nf < 4; ++nf)                        \
            acc[mf][nf] = __builtin_amdgcn_mfma_f32_16x16x32_bf16(ah, Wm[nf], acc[mf][nf], 0, 0, 0); \
        _Pragma("unroll") for (int nf = 0; nf < 4; ++nf)                        \
            acc[mf][nf] = __builtin_amdgcn_mfma_f32_16x16x32_bf16(am, Wh[nf], acc[mf][nf], 0, 0, 0); \
        _Pragma("unroll") for (int nf = 0; nf < 4; ++nf)                        \
            acc[mf][nf] = __builtin_amdgcn_mfma_f32_16x16x32_bf16(am, Wm[nf], acc[mf][nf], 0, 0, 0); \
        _Pragma("unroll") for (int nf = 0; nf < 4; ++nf)                        \
            acc[mf][nf] = __builtin_amdgcn_mfma_f32_16x16x32_bf16(ah, Wl[nf], acc[mf][nf], 0, 0, 0); \
        _Pragma("unroll") for (int nf = 0; nf < 4; ++nf)                        \
            acc[mf][nf] = __builtin_amdgcn_mfma_f32_16x16x32_bf16(al, Wh[nf], acc[mf][nf], 0, 0, 0); \
    } }

    // prologue: x for K-step 0
    LOADX(0)

#pragma unroll 1
    for (int kk = 0; kk < 64; ++kk) {
        __syncthreads();                 // previous tile consumed
        STAGEW()                         // ga holds tile kk
        __syncthreads();                 // tile kk ready
        if (kk + 1 < 64) { LOADX(kk + 1) }   // issue next x loads (hide under MFMA)
        LOADW(kk)                        // W frags for kk (L2-hit; other wave MFMAs)
        DOMFMA()
    }
#undef LOADW
#undef LOADX
#undef STAGEW
#undef DOMFMA

    // ---- epilogue: C/D layout col=lane&15, row=(lane>>4)*4+reg [m89-verified] ----
#pragma unroll
    for (int mf = 0; mf < 8; ++mf)
#pragma unroll
        for (int nf = 0; nf < 4; ++nf) {
            int ic = i0 + wn * 64 + nf * 16 + lr16;
#pragma unroll
            for (int q = 0; q < 4; ++q) {
                int t = t0 + wm * 128 + mf * 16 + kb * 4 + q;
                y[((size_t)t * NB + b) * NI + ic] = acc[mf][nf][q];
            }
        }
}

// ---------------- BN stats pass 1: per-block partial sum/sumsq over 128 rows ----
__global__ __launch_bounds__(256) void red1(const float* __restrict__ y,
                                            float* __restrict__ part) {
    int r0 = blockIdx.x * 128;
    int c  = threadIdx.x;
    float s0 = 0.f, q0 = 0.f, s1 = 0.f, q1 = 0.f;
#pragma unroll 4
    for (int r = 0; r < 128; ++r) {
        float v0 = y[(size_t)(r0 + r) * NI + c];
        float v1 = y[(size_t)(r0 + r) * NI + c + 256];
        s0 += v0; q0 = fmaf(v0, v0, q0);
        s1 += v1; q1 = fmaf(v1, v1, q1);
    }
    part[blockIdx.x * NI + c]            = s0;
    part[blockIdx.x * NI + c + 256]      = s1;
    part[256 * NI + blockIdx.x * NI + c]       = q0;
    part[256 * NI + blockIdx.x * NI + c + 256] = q1;
}

// ---------------- BN stats pass 2: combine partials (double), emit scale/bias ----
__global__ __launch_bounds__(512) void red2(const float* __restrict__ part,
                                            const float* __restrict__ gamma,
                                            const float* __restrict__ bbeta,
                                            float* __restrict__ sb) {
    int c = threadIdx.x;
    double s = 0.0, q = 0.0;
#pragma unroll 8
    for (int p = 0; p < 256; ++p) {
        s += (double)part[p * NI + c];
        q += (double)part[256 * NI + p * NI + c];
    }
    double mean = s / 32768.0;
    double var  = q / 32768.0 - mean * mean;
    double scale = (double)gamma[c] / sqrt(var + 1e-5);
    sb[c]      = (float)scale;
    sb[NI + c] = (float)((double)bbeta[c] - mean * scale);
}

// ---------------- soft-reset LIF scan, in-place over y (=d_out) ----------------
__global__ __launch_bounds__(64) void scan_kern(float* __restrict__ y,
                                                const float* __restrict__ sb,
                                                const float* __restrict__ beta,
                                                const float* __restrict__ U0) {
    int g = blockIdx.x * 64 + threadIdx.x;   // 0..16383 = b*512 + i
    int i = g & (NI - 1);
    float scale = sb[i];
    float bias  = sb[NI + i];
    float bet = beta[i];
    float omb = 1.f - bet;
    float u = U0[g];
    float s = 0.f;
    float* yp = y + g;

    float A[32], Bv[32];
#pragma unroll
    for (int r = 0; r < 32; ++r) A[r] = yp[(size_t)r * 16384];

    for (int t0 = 0; t0 < TT; t0 += 64) {
#pragma unroll
        for (int r = 0; r < 32; ++r) Bv[r] = yp[(size_t)(t0 + 32 + r) * 16384];
#pragma unroll
        for (int r = 0; r < 32; ++r) {
            float z = fmaf(A[r], scale, bias);
            u = fmaf(bet, u - s, omb * z);
            s = (u >= 1.f) ? 1.f : 0.f;
            yp[(size_t)(t0 + r) * 16384] = s;
        }
        if (t0 + 64 < TT) {
#pragma unroll
            for (int r = 0; r < 32; ++r) A[r] = yp[(size_t)(t0 + 64 + r) * 16384];
        }
#pragma unroll
        for (int r = 0; r < 32; ++r) {
            float z = fmaf(Bv[r], scale, bias);
            u = fmaf(bet, u - s, omb * z);
            s = (u >= 1.f) ? 1.f : 0.f;
            yp[(size_t)(t0 + 32 + r) * 16384] = s;
        }
    }
}

extern "C" void kernel_launch(void* const* d_in, const int* in_sizes, int n_in,
                              void* d_out, int out_size, void* d_ws, size_t ws_size,
                              hipStream_t stream) {
    const float* x       = (const float*)d_in[0];
    const float* delay_w = (const float*)d_in[1];
    const float* delay_P = (const float*)d_in[2];
    const float* beta    = (const float*)d_in[3];
    const float* bn_g    = (const float*)d_in[4];
    const float* bn_b    = (const float*)d_in[5];
    const float* U0      = (const float*)d_in[6];
    float* y = (float*)d_out;

    // ws layout (6 MiB total, R10-proven): WF occupies [0, 6 MiB). part/sb ALIAS
    // WF's space — safe because kernels serialize on the stream: dcls writes WF,
    // conv reads WF, THEN red1 clobbers [0,1 MiB) with partials, red2 writes sb.
    // Every buffer fully rewritten before each read -> deterministic under replay.
    short* WF   = (short*)d_ws;
    float* part = (float*)d_ws;
    float* sb   = (float*)d_ws + 2 * 256 * NI;

    dcls_kern<<<dim3(NI * NJ / 256), dim3(256), 0, stream>>>(delay_w, delay_P, WF);
    conv_mfma<<<dim3(TT / 256, NI / 256, NB), dim3(512), 0, stream>>>(x, WF, y);
    red1<<<dim3(TT * NB / 128), dim3(256), 0, stream>>>(y, part);
    red2<<<dim3(1), dim3(512), 0, stream>>>(part, bn_g, bn_b, sb);
    scan_kern<<<dim3(NB * NI / 64), dim3(64), 0, stream>>>(y, sb, beta, U0);
}